// Round 10
// baseline (73527.057 us; speedup 1.0000x reference)
//
#include <hip/hip_runtime.h>
#include <math.h>

// NDDE forward-Euler DDE solve, D=768, N=8192 steps.
// x_{j+1} = x_j + dt * tanh(Wx x_j + Wy x_{j-10} + b),  dt = tau/10.
// Output: trajectory [D][N+1] fp32, out[i*(N+1)+k] = x_k[i].
//
// NUMERICS ARE FROZEN (passes at absmax 16.0 / thr 16.4): fp64-exact dots
// rounded per-dot to fp32; fp32 adds for z; correctly-rounded fp32 tanh via
// fp64; fp32 state update mul-then-add; per-row 32-lane x 24-col ownership,
// FMA order and shuffle tree IDENTICAL to round 5 (20.35 ms best).
//
// Round 10 = r5's exact single-hop tagged-data protocol (poll IS the fetch;
// no flags/RMWs/fences/vmcnt — r6-r9 each proved a variant of those worse),
// with 4x fewer sync participants: 24 WGs x 1024 thr, 32 rows/WG. Step
// completion is a max over 24 detectors instead of 96, and aggregate poll
// traffic drops 4x. Only blockIdx->row bookkeeping changed; every float op
// is bit-identical.

#define DD 768
#define NSTEPS 8192
#define NWG 24
#define NT 1024
#define ROWS_PER_WG 32
#define COLS_PER_LANE 24
#define RING 16

#define RING_OFF 0   // RING * DD * 8B packs in d_ws

__device__ __forceinline__ unsigned long long ld_tag(const unsigned long long* p) {
    return __hip_atomic_load(p, __ATOMIC_RELAXED, __HIP_MEMORY_SCOPE_AGENT);
}

__global__ __launch_bounds__(NT, 1)
void ndde_kernel(const float* __restrict__ x0,
                 const float* __restrict__ tau,
                 const float* __restrict__ Wx,
                 const float* __restrict__ Wy,
                 const float* __restrict__ b,
                 float* __restrict__ out,
                 unsigned long long* __restrict__ ring)
{
    // Transposed f32 LDS history (r5): column i at hist[slot][(i%24)*32+i/24].
    // Reads bank-conflict-free (bank = lane); wave-0 writes 2-way (free).
    __shared__ float hist[RING][DD];     // 48 KB

    const int tid = threadIdx.x;
    const int g   = blockIdx.x;
    const int r   = tid >> 5;            // local row 0..31
    const int c   = tid & 31;            // lane-within-row 0..31
    const int row = g * ROWS_PER_WG + r;
    const int cb  = c * COLS_PER_LANE;

    const float dtf = tau[0] / 10.0f;

    // ---- stage weights as f32 (r5-identical; cvt to f64 at use, exact) ----
    float wxf[COLS_PER_LANE], wyf[COLS_PER_LANE];
    {
        const float* px = Wx + row * DD + cb;
        const float* py = Wy + row * DD + cb;
        #pragma unroll
        for (int i = 0; i < COLS_PER_LANE / 4; ++i) {
            float4 a = *(const float4*)(px + 4 * i);
            wxf[4*i+0] = a.x; wxf[4*i+1] = a.y; wxf[4*i+2] = a.z; wxf[4*i+3] = a.w;
            float4 d2 = *(const float4*)(py + 4 * i);
            wyf[4*i+0] = d2.x; wyf[4*i+1] = d2.y; wyf[4*i+2] = d2.z; wyf[4*i+3] = d2.w;
        }
    }
    #pragma unroll
    for (int i = 0; i < COLS_PER_LANE; ++i) {
        asm volatile("" : "+v"(wxf[i]));
        asm volatile("" : "+v"(wyf[i]));
    }

    const float brow = b[row];
    float xrow = x0[row];                // lane c==0 carries x_j[row]
    if (c == 0) out[row * (NSTEPS + 1) + 0] = xrow;

    for (int j = 0; j < NSTEPS; ++j) {
        // ---- delayed half: y = x_{j-10} from LDS history (r5-identical).
        // Runs before the poll — hides poll start; other waves overlap. ----
        double dy0 = 0.0, dy1 = 0.0;
        if (j <= 10) {
            const float* ys = x0 + cb;
            #pragma unroll
            for (int i = 0; i < COLS_PER_LANE / 4; ++i) {
                float4 v = *(const float4*)(ys + 4 * i);
                dy0 = fma((double)wyf[4*i+0], (double)v.x, dy0);
                dy1 = fma((double)wyf[4*i+1], (double)v.y, dy1);
                dy0 = fma((double)wyf[4*i+2], (double)v.z, dy0);
                dy1 = fma((double)wyf[4*i+3], (double)v.w, dy1);
            }
        } else {
            const float* hs = hist[(j - 10) & (RING - 1)];
            #pragma unroll
            for (int k = 0; k < COLS_PER_LANE; k += 4) {
                float v0 = hs[(k+0)*32 + c];
                float v1 = hs[(k+1)*32 + c];
                float v2 = hs[(k+2)*32 + c];
                float v3 = hs[(k+3)*32 + c];
                dy0 = fma((double)wyf[k+0], (double)v0, dy0);
                dy1 = fma((double)wyf[k+1], (double)v1, dy1);
                dy0 = fma((double)wyf[k+2], (double)v2, dy0);
                dy1 = fma((double)wyf[k+3], (double)v3, dy1);
            }
        }
        double doty = dy0 + dy1;
        #pragma unroll
        for (int off = 1; off < 32; off <<= 1)
            doty += __shfl_xor(doty, off);

        // ---- wave 0: single-hop poll (poll IS the fetch), broadcast ----
        if (j >= 1) {
            if (tid < 64) {
                const unsigned tgt = (unsigned)j;
                const unsigned long long* xs =
                    ring + (j & (RING - 1)) * DD + tid * 12;
                unsigned long long xv[12];
                for (;;) {
                    #pragma unroll
                    for (int m = 0; m < 12; ++m) xv[m] = ld_tag(xs + m);
                    bool ok = true;
                    #pragma unroll
                    for (int m = 0; m < 12; ++m)
                        ok &= ((unsigned)(xv[m] >> 32) == tgt);
                    if (__all(ok)) break;
                }
                float* hsw = hist[j & (RING - 1)];
                #pragma unroll
                for (int m = 0; m < 12; ++m) {
                    int i = tid * 12 + m;
                    hsw[(i % 24) * 32 + (i / 24)] =
                        __uint_as_float((unsigned)xv[m]);
                }
            }
            __syncthreads();
        }

        // ---- live half: Wx · x_j from LDS (r5-identical) ----
        double dx0 = 0.0, dx1 = 0.0;
        if (j == 0) {
            const float* xs = x0 + cb;
            #pragma unroll
            for (int i = 0; i < COLS_PER_LANE / 4; ++i) {
                float4 v = *(const float4*)(xs + 4 * i);
                dx0 = fma((double)wxf[4*i+0], (double)v.x, dx0);
                dx1 = fma((double)wxf[4*i+1], (double)v.y, dx1);
                dx0 = fma((double)wxf[4*i+2], (double)v.z, dx0);
                dx1 = fma((double)wxf[4*i+3], (double)v.w, dx1);
            }
        } else {
            const float* hs = hist[j & (RING - 1)];
            #pragma unroll
            for (int k = 0; k < COLS_PER_LANE; k += 4) {
                float v0 = hs[(k+0)*32 + c];
                float v1 = hs[(k+1)*32 + c];
                float v2 = hs[(k+2)*32 + c];
                float v3 = hs[(k+3)*32 + c];
                dx0 = fma((double)wxf[k+0], (double)v0, dx0);
                dx1 = fma((double)wxf[k+1], (double)v1, dx1);
                dx0 = fma((double)wxf[k+2], (double)v2, dx0);
                dx1 = fma((double)wxf[k+3], (double)v3, dx1);
            }
        }
        double dotx = dx0 + dx1;
        #pragma unroll
        for (int off = 1; off < 32; off <<= 1)
            dotx += __shfl_xor(dotx, off);

        if (c == 0) {
            // z = (dot1_f32 + dot2_f32) + b, all fp32 adds (np's structure)
            float z = __fadd_rn(__fadd_rn((float)dotx, (float)doty), brow);
            float th;
            float az = fabsf(z);
            if (az < 9.3f) th = (float)tanh((double)z);  // correctly-rounded
            else           th = (z > 0.0f) ? 1.0f : -1.0f;
            // x_next = x + dt*F, fp32 mul then fp32 add (no contraction)
            xrow = __fadd_rn(xrow, __fmul_rn(dtf, th));

            // publish: (value|tag) in one relaxed agent-scope 8B store
            unsigned long long pack =
                ((unsigned long long)(unsigned)(j + 1) << 32) |
                (unsigned long long)__float_as_uint(xrow);
            __hip_atomic_store(&ring[((j + 1) & (RING - 1)) * DD + row], pack,
                               __ATOMIC_RELAXED, __HIP_MEMORY_SCOPE_AGENT);

            // trajectory write — off the critical path
            out[row * (NSTEPS + 1) + (j + 1)] = xrow;
        }
    }
}

extern "C" void kernel_launch(void* const* d_in, const int* in_sizes, int n_in,
                              void* d_out, int out_size, void* d_ws, size_t ws_size,
                              hipStream_t stream) {
    (void)in_sizes; (void)n_in; (void)out_size; (void)ws_size;

    const float* x0  = (const float*)d_in[0];
    const float* tau = (const float*)d_in[1];
    const float* Wx  = (const float*)d_in[2];
    const float* Wy  = (const float*)d_in[3];
    const float* b   = (const float*)d_in[4];
    float* out = (float*)d_out;

    unsigned long long* ring = (unsigned long long*)((char*)d_ws + RING_OFF);

    // No memset needed: strict tag==j matching rejects 0xAA poison and stale
    // replay tags (slot j%16 is freshly rewritten long before step j needs it).
    ndde_kernel<<<NWG, NT, 0, stream>>>(x0, tau, Wx, Wy, b, out, ring);
}

// Round 11
// 14946.027 us; speedup vs baseline: 4.9195x; 4.9195x over previous
//
#include <hip/hip_runtime.h>
#include <math.h>

// NDDE forward-Euler DDE solve, D=768, N=8192 steps.
// x_{j+1} = x_j + dt * tanh(Wx x_j + Wy x_{j-10} + b),  dt = tau/10.
// Output: trajectory [D][N+1] fp32, out[i*(N+1)+k] = x_k[i].
//
// NUMERICS ARE FROZEN (passes at absmax 16.0 / thr 16.4): fp64-exact dots
// rounded per-dot to fp32; fp32 adds for z; correctly-rounded fp32 tanh via
// fp64; fp32 state update mul-then-add; per-row 32-lane x 24-col ownership,
// FMA order and shuffle tree IDENTICAL to round 5 (20.35 ms best).
//
// Round 11 = r5 verbatim + ONE change: the single-hop tagged-data poll is
// split across all 4 waves (3 packs/lane each, disjoint, union = 768)
// instead of wave 0 alone sweeping 12 packs/lane. Waves 1-3 were idle at
// the barrier during the poll anyway; now the sweep is 4x shorter, so
// detect quantization (~1.5 sweeps after last publish) shrinks by several
// hundred cycles. Aggregate MALL request rate is ~unchanged (384 waves x 24
// lines vs 96 x 96). Everything else — arithmetic, publish, LDS layout,
// topology — is bit-identical r5.
//
// Protocol lessons encoded from failed rounds: no fences (r3: wbl2/inv
// stall), no atomic RMWs (r7: same-line serialization), no extra detect hop
// (r9: serial RT adds), no setprio on spin waves (r6: starvation), no
// replication (r8: L2/LDS thrash), VGPR budget must fit staged weights
// (r4/r10: spills dominate everything).

#define DD 768
#define NSTEPS 8192
#define NWG 96
#define NT 256
#define ROWS_PER_WG 8
#define COLS_PER_LANE 24
#define RING 16

#define RING_OFF 0   // RING * DD * 8B packs in d_ws

__device__ __forceinline__ unsigned long long ld_tag(const unsigned long long* p) {
    return __hip_atomic_load(p, __ATOMIC_RELAXED, __HIP_MEMORY_SCOPE_AGENT);
}

__global__ __launch_bounds__(NT, 1)
void ndde_kernel(const float* __restrict__ x0,
                 const float* __restrict__ tau,
                 const float* __restrict__ Wx,
                 const float* __restrict__ Wy,
                 const float* __restrict__ b,
                 float* __restrict__ out,
                 unsigned long long* __restrict__ ring)
{
    // Transposed f32 LDS history (r5): column i at hist[slot][(i%24)*32+i/24].
    // Reads bank-conflict-free (bank = lane); broadcast writes ~24-way but
    // only 3/lane once per step (measured cost: ~24 cy/step — negligible).
    __shared__ float hist[RING][DD];     // 48 KB

    const int tid = threadIdx.x;
    const int g   = blockIdx.x;
    const int r   = tid >> 5;            // local row 0..7
    const int c   = tid & 31;            // lane-within-row 0..31
    const int row = g * ROWS_PER_WG + r;
    const int cb  = c * COLS_PER_LANE;

    const float dtf = tau[0] / 10.0f;

    // ---- stage weights as f32 (r5-identical; cvt to f64 at use, exact) ----
    float wxf[COLS_PER_LANE], wyf[COLS_PER_LANE];
    {
        const float* px = Wx + row * DD + cb;
        const float* py = Wy + row * DD + cb;
        #pragma unroll
        for (int i = 0; i < COLS_PER_LANE / 4; ++i) {
            float4 a = *(const float4*)(px + 4 * i);
            wxf[4*i+0] = a.x; wxf[4*i+1] = a.y; wxf[4*i+2] = a.z; wxf[4*i+3] = a.w;
            float4 d2 = *(const float4*)(py + 4 * i);
            wyf[4*i+0] = d2.x; wyf[4*i+1] = d2.y; wyf[4*i+2] = d2.z; wyf[4*i+3] = d2.w;
        }
    }
    #pragma unroll
    for (int i = 0; i < COLS_PER_LANE; ++i) {
        asm volatile("" : "+v"(wxf[i]));
        asm volatile("" : "+v"(wyf[i]));
    }

    const float brow = b[row];
    float xrow = x0[row];                // lane c==0 carries x_j[row]
    if (c == 0) out[row * (NSTEPS + 1) + 0] = xrow;

    for (int j = 0; j < NSTEPS; ++j) {
        // ---- delayed half: y = x_{j-10} from LDS history (r5-identical).
        // Runs before the poll so it overlaps other WGs' publish window. ----
        double dy0 = 0.0, dy1 = 0.0;
        if (j <= 10) {
            const float* ys = x0 + cb;
            #pragma unroll
            for (int i = 0; i < COLS_PER_LANE / 4; ++i) {
                float4 v = *(const float4*)(ys + 4 * i);
                dy0 = fma((double)wyf[4*i+0], (double)v.x, dy0);
                dy1 = fma((double)wyf[4*i+1], (double)v.y, dy1);
                dy0 = fma((double)wyf[4*i+2], (double)v.z, dy0);
                dy1 = fma((double)wyf[4*i+3], (double)v.w, dy1);
            }
        } else {
            const float* hs = hist[(j - 10) & (RING - 1)];
            #pragma unroll
            for (int k = 0; k < COLS_PER_LANE; k += 4) {
                float v0 = hs[(k+0)*32 + c];
                float v1 = hs[(k+1)*32 + c];
                float v2 = hs[(k+2)*32 + c];
                float v3 = hs[(k+3)*32 + c];
                dy0 = fma((double)wyf[k+0], (double)v0, dy0);
                dy1 = fma((double)wyf[k+1], (double)v1, dy1);
                dy0 = fma((double)wyf[k+2], (double)v2, dy0);
                dy1 = fma((double)wyf[k+3], (double)v3, dy1);
            }
        }
        double doty = dy0 + dy1;
        #pragma unroll
        for (int off = 1; off < 32; off <<= 1)
            doty += __shfl_xor(doty, off);

        // ---- ALL 4 waves: single-hop poll of disjoint 3-pack/lane subsets
        // (union = 768), then each broadcasts its subset to LDS. Sweep =
        // 3 MALL loads (vs r5's 12) -> detect quantization shrinks ~4x. ----
        if (j >= 1) {
            const int w = tid >> 6;          // wave 0..3
            const int l = tid & 63;          // lane 0..63
            const unsigned tgt = (unsigned)j;
            const unsigned long long* xs =
                ring + (j & (RING - 1)) * DD + w * 192 + l * 3;
            unsigned long long xv0, xv1, xv2;
            for (;;) {
                xv0 = ld_tag(xs + 0);
                xv1 = ld_tag(xs + 1);
                xv2 = ld_tag(xs + 2);
                bool ok = ((unsigned)(xv0 >> 32) == tgt) &
                          ((unsigned)(xv1 >> 32) == tgt) &
                          ((unsigned)(xv2 >> 32) == tgt);
                if (__all(ok)) break;
            }
            float* hsw = hist[j & (RING - 1)];
            const int i0 = w * 192 + l * 3;
            hsw[((i0+0) % 24) * 32 + ((i0+0) / 24)] = __uint_as_float((unsigned)xv0);
            hsw[((i0+1) % 24) * 32 + ((i0+1) / 24)] = __uint_as_float((unsigned)xv1);
            hsw[((i0+2) % 24) * 32 + ((i0+2) / 24)] = __uint_as_float((unsigned)xv2);
            __syncthreads();
        }

        // ---- live half: Wx · x_j from LDS (r5-identical) ----
        double dx0 = 0.0, dx1 = 0.0;
        if (j == 0) {
            const float* xs = x0 + cb;
            #pragma unroll
            for (int i = 0; i < COLS_PER_LANE / 4; ++i) {
                float4 v = *(const float4*)(xs + 4 * i);
                dx0 = fma((double)wxf[4*i+0], (double)v.x, dx0);
                dx1 = fma((double)wxf[4*i+1], (double)v.y, dx1);
                dx0 = fma((double)wxf[4*i+2], (double)v.z, dx0);
                dx1 = fma((double)wxf[4*i+3], (double)v.w, dx1);
            }
        } else {
            const float* hs = hist[j & (RING - 1)];
            #pragma unroll
            for (int k = 0; k < COLS_PER_LANE; k += 4) {
                float v0 = hs[(k+0)*32 + c];
                float v1 = hs[(k+1)*32 + c];
                float v2 = hs[(k+2)*32 + c];
                float v3 = hs[(k+3)*32 + c];
                dx0 = fma((double)wxf[k+0], (double)v0, dx0);
                dx1 = fma((double)wxf[k+1], (double)v1, dx1);
                dx0 = fma((double)wxf[k+2], (double)v2, dx0);
                dx1 = fma((double)wxf[k+3], (double)v3, dx1);
            }
        }
        double dotx = dx0 + dx1;
        #pragma unroll
        for (int off = 1; off < 32; off <<= 1)
            dotx += __shfl_xor(dotx, off);

        if (c == 0) {
            // z = (dot1_f32 + dot2_f32) + b, all fp32 adds (np's structure)
            float z = __fadd_rn(__fadd_rn((float)dotx, (float)doty), brow);
            float th;
            float az = fabsf(z);
            if (az < 9.3f) th = (float)tanh((double)z);  // correctly-rounded
            else           th = (z > 0.0f) ? 1.0f : -1.0f;
            // x_next = x + dt*F, fp32 mul then fp32 add (no contraction)
            xrow = __fadd_rn(xrow, __fmul_rn(dtf, th));

            // publish: (value|tag) in one relaxed agent-scope 8B store
            unsigned long long pack =
                ((unsigned long long)(unsigned)(j + 1) << 32) |
                (unsigned long long)__float_as_uint(xrow);
            __hip_atomic_store(&ring[((j + 1) & (RING - 1)) * DD + row], pack,
                               __ATOMIC_RELAXED, __HIP_MEMORY_SCOPE_AGENT);

            // trajectory write — off the critical path
            out[row * (NSTEPS + 1) + (j + 1)] = xrow;
        }
    }
}

extern "C" void kernel_launch(void* const* d_in, const int* in_sizes, int n_in,
                              void* d_out, int out_size, void* d_ws, size_t ws_size,
                              hipStream_t stream) {
    (void)in_sizes; (void)n_in; (void)out_size; (void)ws_size;

    const float* x0  = (const float*)d_in[0];
    const float* tau = (const float*)d_in[1];
    const float* Wx  = (const float*)d_in[2];
    const float* Wy  = (const float*)d_in[3];
    const float* b   = (const float*)d_in[4];
    float* out = (float*)d_out;

    unsigned long long* ring = (unsigned long long*)((char*)d_ws + RING_OFF);

    // No memset needed: strict tag==j matching rejects 0xAA poison and stale
    // replay tags (slot j%16 is freshly rewritten long before step j needs it).
    ndde_kernel<<<NWG, NT, 0, stream>>>(x0, tau, Wx, Wy, b, out, ring);
}